// Round 16
// baseline (231.773 us; speedup 1.0000x reference)
//
#include <hip/hip_runtime.h>
#include <hip/hip_bf16.h>
#include <math.h>

// MKAFullAttention: B=4, T=1024, D=1024, H=16, DH=64, BETA=0.9
// Round 16: ema_kv_carry merged into ema_kv_fix (per-block Horner carry from
//           local chunk-ends; dispatches 8->7, ends[] now read-only).
//           Everything else identical to R15.
//   - KV2 = EMA(K1,V1) (EMA linearity), router fused via wqrT = rw1^T.wq.
//   - l3 stream analytic: attend(l3) = broadcast(l3@wv).

#define B_ 4
#define T_ 1024
#define D_ 1024
#define H_ 16
#define DH_ 64
#define M_ 4096

#define ECH 16
#define NCH 64

typedef __attribute__((ext_vector_type(8))) short bf16x8;
typedef __attribute__((ext_vector_type(4))) short s16x4;
typedef __attribute__((ext_vector_type(4))) float f32x4;

__device__ inline short f2b(float f) {
  __hip_bfloat16 h = __float2bfloat16(f);
  return *reinterpret_cast<short*>(&h);
}

__device__ inline float b2f(unsigned short u) {
  unsigned int x = ((unsigned int)u) << 16;
  return *reinterpret_cast<float*>(&x);
}

__device__ inline void gload_lds16(const short* g, short* l) {
  __builtin_amdgcn_global_load_lds(
      (const __attribute__((address_space(1))) unsigned int*)g,
      (__attribute__((address_space(3))) unsigned int*)l, 16, 0, 0);
}

// ---------------- prep: weight transposes + x/wq bf16 converts (one dispatch) ----------------
__global__ __launch_bounds__(256) void prep_kernel(
    const float* __restrict__ w0, const float* __restrict__ w1,
    const float* __restrict__ w2, const float* __restrict__ w3,
    const float* __restrict__ w4, const float* __restrict__ x,
    const float* __restrict__ wq,
    short* __restrict__ t0, short* __restrict__ t1, short* __restrict__ t2,
    short* __restrict__ t3, short* __restrict__ t4,
    short* __restrict__ xb, short* __restrict__ wqB) {
  int z = blockIdx.z;
  if (z < 5) {
    const float* W = (z == 0) ? w0 : (z == 1) ? w1 : (z == 2) ? w2 : (z == 3) ? w3 : w4;
    short* Wt = (z == 0) ? t0 : (z == 1) ? t1 : (z == 2) ? t2 : (z == 3) ? t3 : t4;
    int cols = (z == 4) ? 512 : 1024;
    int c0 = blockIdx.x * 32, r0 = blockIdx.y * 32;
    if (c0 >= cols) return;
    __shared__ float tile[32][33];
    int tc = threadIdx.x & 31, tr8 = threadIdx.x >> 5;
#pragma unroll
    for (int i = 0; i < 4; ++i)
      tile[tr8 + i * 8][tc] = W[(size_t)(r0 + tr8 + i * 8) * cols + c0 + tc];
    __syncthreads();
#pragma unroll
    for (int i = 0; i < 4; ++i) {
      int rr = tr8 + i * 8;
      Wt[(size_t)(c0 + rr) * 1024 + r0 + tc] = f2b(tile[tc][rr]);
    }
  } else if (z == 5) {
    int blk = blockIdx.y * 32 + blockIdx.x;  // 0..1023
#pragma unroll
    for (int i = 0; i < 4; ++i) {
      int idx = blk * 1024 + i * 256 + threadIdx.x;  // float4 index, 1M total
      float4 v = ((const float4*)x)[idx];
      s16x4 o;
      o[0] = f2b(v.x); o[1] = f2b(v.y); o[2] = f2b(v.z); o[3] = f2b(v.w);
      ((s16x4*)xb)[idx] = o;
    }
  } else {
    int idx = (blockIdx.y * 32 + blockIdx.x) * 256 + threadIdx.x;  // 256K float4
    float4 v = ((const float4*)wq)[idx];
    s16x4 o;
    o[0] = f2b(v.x); o[1] = f2b(v.y); o[2] = f2b(v.z); o[3] = f2b(v.w);
    ((s16x4*)wqB)[idx] = o;
  }
}

// ---------------- post-GEMM: EMA chunk-ends + router softmax + v3 (one dispatch) ----------------
// blocks [0,2048): ema local ends; [2048,3072): router; [3072,3088): v3.
__global__ __launch_bounds__(256) void post_gemm_kernel(
    const short* __restrict__ QKV, float* __restrict__ ends,
    const float* __restrict__ rb1, const float* __restrict__ rw2,
    const float* __restrict__ rb2, float* __restrict__ lam,
    const float* __restrict__ l3, const float* __restrict__ wv,
    float* __restrict__ v3) {
  int bx = blockIdx.x;
  if (bx < 2048) {
    int idx = bx * 256 + threadIdx.x;  // B*NCH*2048 = 524288
    int col = idx & 2047;
    int ch = (idx >> 11) & (NCH - 1);
    int b = idx >> 17;
    const short* sp = QKV + (size_t)(b * T_ + ch * ECH) * 3584 + 1024 + col;
    float y = 0.f;
#pragma unroll
    for (int t = 0; t < ECH; ++t)
      y = 0.9f * y + 0.1f * b2f((unsigned short)sp[(size_t)t * 3584]);
    ends[(size_t)((b << 6) + ch) * 2048 + col] = y;  // LOCAL chunk end
    return;
  }
  if (bx >= 3072) {
    int idx = (bx - 3072) * 256 + threadIdx.x;  // B*D = 4096
    int b = idx >> 10;
    int col = idx & 1023;
    const float* xr = l3 + (size_t)b * D_;
    float acc = 0.f;
#pragma unroll 8
    for (int k = 0; k < D_; ++k) acc += xr[k] * wv[(size_t)k * D_ + col];
    v3[idx] = acc;
    return;
  }
  // router
  int wave = ((bx - 2048) * 256 + threadIdx.x) >> 6;
  int lane = threadIdx.x & 63;
  const short* hr = QKV + (size_t)wave * 3584 + 3072;
  float s0 = 0.f, s1 = 0.f, s2 = 0.f;
#pragma unroll
  for (int u = 0; u < 8; ++u) {
    int hcol = u * 64 + lane;
    float vv = b2f((unsigned short)hr[hcol]) + rb1[hcol];
    float gl = 0.5f * vv * (1.0f + erff(vv * 0.70710678118654752f));
    s0 += gl * rw2[hcol * 3 + 0];
    s1 += gl * rw2[hcol * 3 + 1];
    s2 += gl * rw2[hcol * 3 + 2];
  }
#pragma unroll
  for (int off = 32; off; off >>= 1) {
    s0 += __shfl_xor(s0, off);
    s1 += __shfl_xor(s1, off);
    s2 += __shfl_xor(s2, off);
  }
  if (lane == 0) {
    float a = s0 + rb2[0], bb = s1 + rb2[1], c = s2 + rb2[2];
    float m = fmaxf(fmaxf(a, bb), c);
    float e0 = expf(a - m), e1 = expf(bb - m), e2 = expf(c - m);
    float inv = 1.0f / (e0 + e1 + e2);
    lam[(size_t)wave * 3 + 0] = e0 * inv;
    lam[(size_t)wave * 3 + 1] = e1 * inv;
    lam[(size_t)wave * 3 + 2] = e2 * inv;
  }
}

// ---------------- EMA fix (carry computed in-block via Horner over local ends) ----------------
// G_ch = sum_{i<ch} bE^(ch-1-i) * e_i  — Horner ascending i: G = G*bE + e_i.
// ends[] is read-only here (local chunk ends from post_gemm).
__global__ __launch_bounds__(256) void ema_kv_fix_kernel(const short* __restrict__ QKV,
                                                         const float* __restrict__ ends,
                                                         short* __restrict__ KV2) {
  int idx = blockIdx.x * 256 + threadIdx.x;  // 524288
  int col = idx & 2047;
  int ch = (idx >> 11) & (NCH - 1);
  int b = idx >> 17;
  const float bE = 0.1853020188851841f;  // 0.9^16
  float G = 0.f;
  for (int i = 0; i < ch; ++i)  // uniform per block (ch constant within a block)
    G = G * bE + ends[(size_t)((b << 6) + i) * 2048 + col];
  const short* sp = QKV + (size_t)(b * T_ + ch * ECH) * 3584 + 1024 + col;
  short* dp = KV2 + (size_t)(b * T_ + ch * ECH) * 2048 + col;
  float y = G;
#pragma unroll
  for (int t = 0; t < ECH; ++t) {
    y = 0.9f * y + 0.1f * b2f((unsigned short)sp[(size_t)t * 3584]);
    dp[(size_t)t * 2048] = f2b(y);
  }
}

// ---------------- bf16 MFMA GEMM: C[M,N] = A[M,K](lda) @ Bt[N,K]^T ----------------
template <int NB, bool SWZ>
__global__ __launch_bounds__(256) void gemm_bt(const short* __restrict__ A, int lda,
                                               const short* __restrict__ Bt,
                                               float* __restrict__ Cf,
                                               short* __restrict__ Cb,
                                               int Ndim, int Kdim) {
  __shared__ short As[128 * 64];
  __shared__ short Bs[NB * 64];
  constexpr int NW = NB / 64;
  constexpr int NF = 4;                    // n-frags per wave: always 64 cols
  constexpr int MF = (NW == 2) ? 4 : 2;
  int tid = threadIdx.x;
  int w = tid >> 6, l = tid & 63;
  int lg = l >> 4, ll = l & 15;
  int wr = (NW == 2) ? (w >> 1) : w;
  int wc = (NW == 2) ? (w & 1) : 0;

  int bx = blockIdx.x, by = blockIdx.y;
  if (SWZ) {
    int nx = gridDim.x;
    int nwg = nx * gridDim.y;
    int cpx = nwg >> 3;  // nwg % 8 == 0
    int lin = by * nx + bx;
    int lin2 = (lin & 7) * cpx + (lin >> 3);
    bx = lin2 % nx;
    by = lin2 / nx;
  }
  int row0 = by * 128, col0 = bx * NB;

  f32x4 acc[MF][NF];
#pragma unroll
  for (int m = 0; m < MF; ++m)
#pragma unroll
    for (int n = 0; n < NF; ++n) acc[m][n] = (f32x4){0.f, 0.f, 0.f, 0.f};

  for (int k0 = 0; k0 < Kdim; k0 += 64) {
    __syncthreads();
#pragma unroll
    for (int it = 0; it < 4; ++it) {
      int s = it * 256 + w * 64 + l;
      int r = s >> 3;
      int c = (s & 7) ^ (r & 7);
      gload_lds16(A + (size_t)(row0 + r) * lda + k0 + c * 8, &As[(it * 256 + w * 64) * 8]);
    }
#pragma unroll
    for (int it = 0; it < NB / 32; ++it) {
      int s = it * 256 + w * 64 + l;
      int r = s >> 3;
      int c = (s & 7) ^ (r & 7);
      gload_lds16(Bt + (size_t)(col0 + r) * Kdim + k0 + c * 8, &Bs[(it * 256 + w * 64) * 8]);
    }
    __syncthreads();
#pragma unroll
    for (int ks = 0; ks < 2; ++ks) {
      bf16x8 af[MF], bfr[NF];
#pragma unroll
      for (int m = 0; m < MF; ++m) {
        int r = wr * (MF * 16) + m * 16 + ll;
        af[m] = *(const bf16x8*)&As[r * 64 + (((ks * 4 + lg) ^ (r & 7)) << 3)];
      }
#pragma unroll
      for (int n = 0; n < NF; ++n) {
        int r = wc * 64 + n * 16 + ll;
        bfr[n] = *(const bf16x8*)&Bs[r * 64 + (((ks * 4 + lg) ^ (r & 7)) << 3)];
      }
#pragma unroll
      for (int m = 0; m < MF; ++m)
#pragma unroll
        for (int n = 0; n < NF; ++n)
          acc[m][n] = __builtin_amdgcn_mfma_f32_16x16x32_bf16(af[m], bfr[n], acc[m][n], 0, 0, 0);
    }
  }
#pragma unroll
  for (int m = 0; m < MF; ++m) {
    int gr = row0 + wr * (MF * 16) + m * 16 + lg * 4;
#pragma unroll
    for (int n = 0; n < NF; ++n) {
      int gc = col0 + wc * 64 + n * 16 + ll;
#pragma unroll
      for (int r = 0; r < 4; ++r) {
        float vv = acc[m][n][r];
        if (Cf) Cf[(size_t)(gr + r) * Ndim + gc] = vv;
        if (Cb) Cb[(size_t)(gr + r) * Ndim + gc] = f2b(vv);
      }
    }
  }
}

// ---------------- fused dual-stream MFMA flash attention (R11/R8 version) ----------------
__global__ __launch_bounds__(256) void attn_fused_kernel(
    const short* __restrict__ q, int ldq,
    const short* __restrict__ k1, const short* __restrict__ v1, int ld1,
    const short* __restrict__ k2, const short* __restrict__ v2, int ld2,
    const float* __restrict__ lam, const float* __restrict__ v3,
    short* __restrict__ mixedb) {
  __shared__ short Ks[2][64][64];   // [stream][key][dh], k8 XOR swizzle (linear dest)
  __shared__ short Vt[2][64][64];   // [stream][dh][key], dword XOR swizzle
  __shared__ short Ps[4][16][64];   // per-wave P, kt XOR swizzle

  int bid = blockIdx.x;
  int half = bid >> 9, p = bid & 511;
  int bh = p & 63;
  int j = p >> 6;
  int qb = half ? (15 - j) : j;
  int b = bh >> 4, h = bh & 15;
  int q0 = qb * 64;
  int tid = threadIdx.x;
  int w = tid >> 6, l = tid & 63;
  int lg = l >> 4, ll = l & 15;

  int qw0 = q0 + w * 16;
  bf16x8 qf[2];
  {
    const short* qr = q + (size_t)(b * T_ + qw0 + ll) * ldq + h * DH_;
    qf[0] = *(const bf16x8*)&qr[lg * 8];
    qf[1] = *(const bf16x8*)&qr[32 + lg * 8];
  }

  float m_[2][4];
  f32x4 o[2][4];
  f32x4 ol[2];
#pragma unroll
  for (int s = 0; s < 2; ++s) {
#pragma unroll
    for (int r = 0; r < 4; ++r) m_[s][r] = -1e30f;
#pragma unroll
    for (int db = 0; db < 4; ++db) o[s][db] = (f32x4){0.f, 0.f, 0.f, 0.f};
    ol[s] = (f32x4){0.f, 0.f, 0.f, 0.f};
  }

  bf16x8 ones;
#pragma unroll
  for (int jj = 0; jj < 8; ++jj) ones[jj] = (short)0x3F80;  // 1.0bf16

  const float SC = 0.125f * 1.44269504f;  // scale * log2(e)
  int nt = qb + 1;
  for (int t64 = 0; t64 < nt; ++t64) {
    int key0 = t64 * 64;
    __syncthreads();
#pragma unroll
    for (int s = 0; s < 2; ++s) {
      const short* kp = s ? k2 : k1;
      const short* vp = s ? v2 : v1;
      int ld = s ? ld2 : ld1;
#pragma unroll
      for (int it = 0; it < 2; ++it) {
        int e = it * 256 + w * 64 + l;
        int r = e >> 3;
        int cs = (e & 7) ^ (r & 7);
        gload_lds16(kp + (size_t)(b * T_ + key0 + r) * ld + h * DH_ + cs * 8,
                    (short*)Ks[s] + (it * 256 + w * 64) * 8);
      }
      {
        int kp2 = tid >> 3, c8 = tid & 7;
        size_t gi = (size_t)(b * T_ + key0 + kp2 * 2) * ld + h * DH_ + c8 * 8;
        bf16x8 va = *(const bf16x8*)&vp[gi];
        bf16x8 vb = *(const bf16x8*)&vp[gi + ld];
        unsigned int* Vtd = (unsigned int*)Vt[s];
#pragma unroll
        for (int jj = 0; jj < 8; ++jj) {
          int dh = c8 * 8 + jj;
          int X = ((dh ^ (dh >> 3)) & 7) << 2;
          Vtd[dh * 32 + (kp2 ^ X)] =
              ((unsigned int)(unsigned short)va[jj]) |
              (((unsigned int)(unsigned short)vb[jj]) << 16);
        }
      }
    }
    __syncthreads();
    if (key0 > qw0 + 15) continue;  // wave fully masked (uniform per wave)

#pragma unroll
    for (int s = 0; s < 2; ++s) {
      // ---- QK^T: 8 MFMA ----
      f32x4 c[4];
#pragma unroll
      for (int kt = 0; kt < 4; ++kt) c[kt] = (f32x4){0.f, 0.f, 0.f, 0.f};
      __builtin_amdgcn_s_setprio(1);
#pragma unroll
      for (int kt = 0; kt < 4; ++kt) {
        int kr = kt * 16 + ll;
        bf16x8 kfa = *(const bf16x8*)&Ks[s][kr][((lg ^ (kr & 7)) << 3)];
        bf16x8 kfb = *(const bf16x8*)&Ks[s][kr][(((4 + lg) ^ (kr & 7)) << 3)];
        c[kt] = __builtin_amdgcn_mfma_f32_16x16x32_bf16(qf[0], kfa, c[kt], 0, 0, 0);
        c[kt] = __builtin_amdgcn_mfma_f32_16x16x32_bf16(qf[1], kfb, c[kt], 0, 0, 0);
      }
      __builtin_amdgcn_s_setprio(0);

      // ---- scores (interior tiles skip mask) ----
      float sv[4][4];
      if (key0 + 63 <= qw0) {
#pragma unroll
        for (int r = 0; r < 4; ++r)
#pragma unroll
          for (int kt = 0; kt < 4; ++kt) sv[r][kt] = c[kt][r] * SC;
      } else {
#pragma unroll
        for (int r = 0; r < 4; ++r) {
          int grow = qw0 + lg * 4 + r;
#pragma unroll
          for (int kt = 0; kt < 4; ++kt) {
            float t = c[kt][r] * SC;
            sv[r][kt] = (key0 + kt * 16 + ll > grow) ? -1e30f : t;
          }
        }
      }

      // ---- row max + defer-max rescale ----
      float mx[4];
#pragma unroll
      for (int r = 0; r < 4; ++r) {
        float m0 = fmaxf(fmaxf(sv[r][0], sv[r][1]), fmaxf(sv[r][2], sv[r][3]));
        m0 = fmaxf(m0, __shfl_xor(m0, 1));
        m0 = fmaxf(m0, __shfl_xor(m0, 2));
        m0 = fmaxf(m0, __shfl_xor(m0, 4));
        m0 = fmaxf(m0, __shfl_xor(m0, 8));
        mx[r] = m0;
      }
      int grew = 0;
#pragma unroll
      for (int r = 0; r < 4; ++r) grew |= (mx[r] > m_[s][r] + 8.f) ? 1 : 0;
      if (__any(grew)) {
#pragma unroll
        for (int r = 0; r < 4; ++r) {
          float nm = fmaxf(m_[s][r], mx[r]);
          float al = exp2f(m_[s][r] - nm);
          m_[s][r] = nm;
          ol[s][r] *= al;
#pragma unroll
          for (int db = 0; db < 4; ++db) o[s][db][r] *= al;
        }
      }

      // ---- P = exp2(sv - m), write to LDS ----
#pragma unroll
      for (int r = 0; r < 4; ++r) {
        float mr = m_[s][r];
        int prow = lg * 4 + r;
#pragma unroll
        for (int kt = 0; kt < 4; ++kt) {
          float pv = exp2f(sv[r][kt] - mr);
          Ps[w][prow][((kt ^ lg) << 4) + ll] = f2b(pv);
        }
      }
      asm volatile("s_waitcnt lgkmcnt(0)" ::: "memory");
      __builtin_amdgcn_sched_barrier(0);

      // ---- PV: 8 MFMA + 2 for row-sum ----
      __builtin_amdgcn_s_setprio(1);
#pragma unroll
      for (int ks = 0; ks < 2; ++ks) {
        int pswz = (ks * 32 + lg * 8) ^ ((ll >> 2) << 4);
        bf16x8 pf = *(const bf16x8*)&Ps[w][ll][pswz];
        const unsigned int* Vtd = (const unsigned int*)Vt[s];
        ol[s] = __builtin_amdgcn_mfma_f32_16x16x32_bf16(pf, ones, ol[s], 0, 0, 0);
#pragma unroll
        for (int db = 0; db < 4; ++db) {
          int dh = db * 16 + ll;
          int X = ((dh ^ (dh >> 3)) & 7) << 2;
          bf16x8 vf = *(const bf16x8*)&Vtd[dh * 32 + ((ks * 16 + lg * 4) ^ X)];
          o[s][db] = __builtin_amdgcn_mfma_f32_16x16x32_bf16(pf, vf, o[s][db], 0, 0, 0);
        }
      }
      __builtin_amdgcn_s_setprio(0);
      __builtin_amdgcn_sched_barrier(0);
    }
  }

  // ---- epilogue ----
#pragma unroll
  for (int r = 0; r < 4; ++r) {
    int grow = qw0 + lg * 4 + r;
    const float* lr = lam + (size_t)(b * T_ + grow) * 3;
    float w0 = lr[0] / ol[0][r];
    float w1 = lr[1] / ol[1][r];
    float w2 = lr[2];
#pragma unroll
    for (int db = 0; db < 4; ++db) {
      int dcol = h * DH_ + db * 16 + ll;
      float val = w0 * o[0][db][r] + w1 * o[1][db][r] + w2 * v3[(b << 10) + dcol];
      mixedb[(size_t)(b * T_ + grow) * D_ + dcol] = f2b(val);
    }
  }
}

extern "C" void kernel_launch(void* const* d_in, const int* in_sizes, int n_in,
                              void* d_out, int out_size, void* d_ws, size_t ws_size,
                              hipStream_t stream) {
  const float* x = (const float*)d_in[0];
  const float* l3m = (const float*)d_in[1];
  const float* wq = (const float*)d_in[2];
  const float* wk = (const float*)d_in[3];
  const float* wv = (const float*)d_in[4];
  const float* wo = (const float*)d_in[5];
  const float* rw1 = (const float*)d_in[6];
  const float* rb1 = (const float*)d_in[7];
  const float* rw2 = (const float*)d_in[8];
  const float* rb2 = (const float*)d_in[9];

  float* out = (float*)d_out;
  float* lam = out + (size_t)M_ * D_;  // output tail: [4096,3]

  float* ws = (float*)d_ws;
  short* QKV = (short*)ws;              // [4096][3584] bf16 = 14,680,064 shorts
  float* v3 = ws + 7340032;             // 4096
  float* ends = ws + 7344128;           // 524288 floats (EMA local chunk ends)
  short* sb = (short*)(ws + 7868416);
  short* xb = sb;                       // 4M shorts
  short* KV2 = sb + 4194304;            // 8M: [4096][2048]
  short* mixedb = sb + 12582912;        // 4M
  short* wqkvT = sb + 16777216;         // [3584][1024] = 3,670,016 shorts
  short* woT = sb + 20447232;           // 1M
  short* rw1T = sb + 21495808;          // 512K
  short* wqB = sb + 22020096;           // 1M: bf16(wq) non-transposed

  dim3 blk(256);

  // prep: weight transposes (z<5) + x cvt (z=5) + wq cvt (z=6)
  prep_kernel<<<dim3(32, 32, 7), blk, 0, stream>>>(
      wq, wk, wv, wo, rw1, x, wq,
      wqkvT, wqkvT + 1024 * 1024, wqkvT + 2048 * 1024, woT, rw1T, xb, wqB);

  // wqrT[j][k] = sum_d rw1[d][j] * wq[k][d]  (rows 3072..3583 of wqkvT)
  gemm_bt<64, false><<<dim3(16, 4), blk, 0, stream>>>(rw1T, 1024, wqB, (float*)nullptr,
                                                      wqkvT + 3072 * 1024, 1024, 1024);

  // main GEMM: [q|k1|v1|hdn] = xb @ wqkvT^T  (N=3584, 896 blocks, XCD swizzle)
  gemm_bt<128, true><<<dim3(28, 32), blk, 0, stream>>>(xb, 1024, wqkvT, (float*)nullptr,
                                                       QKV, 3584, 1024);

  // EMA local chunk-ends + router softmax + v3 (one dispatch, shares warm QKV)
  post_gemm_kernel<<<3088, blk, 0, stream>>>(QKV, ends, rb1, rw2, rb2, lam, l3m, wv, v3);

  // EMA fix (carry via in-block Horner over local ends) -> KV2
  ema_kv_fix_kernel<<<2048, blk, 0, stream>>>(QKV, ends, KV2);

  // fused dual-stream attention -> mixedb (bf16)
  attn_fused_kernel<<<1024, blk, 0, stream>>>(QKV, 3584,
                                              QKV + 1024, QKV + 2048, 3584,
                                              KV2, KV2 + 1024, 2048,
                                              lam, v3, mixedb);

  // out = mixedb @ woT (512 blocks, XCD swizzle)
  gemm_bt<64, true><<<dim3(16, 32), blk, 0, stream>>>(mixedb, 1024, woT, out,
                                                      (short*)nullptr, 1024, 1024);
}

// Round 17
// 222.673 us; speedup vs baseline: 1.0409x; 1.0409x over previous
//
#include <hip/hip_runtime.h>
#include <hip/hip_bf16.h>
#include <math.h>

// MKAFullAttention: B=4, T=1024, D=1024, H=16, DH=64, BETA=0.9
// Round 17: exact revert to R15 (best measured, 223.0us). R16's carry-into-fix
//           merge regressed (+8.7us: avg-32 redundant L2 loads/thread in the
//           runtime-bound Horner loop beat the 8us kernel+gap it deleted).
//   - KV2 = EMA(K1,V1) (EMA linearity), router fused via wqrT = rw1^T.wq.
//   - l3 stream analytic: attend(l3) = broadcast(l3@wv).

#define B_ 4
#define T_ 1024
#define D_ 1024
#define H_ 16
#define DH_ 64
#define M_ 4096

#define ECH 16
#define NCH 64

typedef __attribute__((ext_vector_type(8))) short bf16x8;
typedef __attribute__((ext_vector_type(4))) short s16x4;
typedef __attribute__((ext_vector_type(4))) float f32x4;

__device__ inline short f2b(float f) {
  __hip_bfloat16 h = __float2bfloat16(f);
  return *reinterpret_cast<short*>(&h);
}

__device__ inline float b2f(unsigned short u) {
  unsigned int x = ((unsigned int)u) << 16;
  return *reinterpret_cast<float*>(&x);
}

__device__ inline void gload_lds16(const short* g, short* l) {
  __builtin_amdgcn_global_load_lds(
      (const __attribute__((address_space(1))) unsigned int*)g,
      (__attribute__((address_space(3))) unsigned int*)l, 16, 0, 0);
}

// ---------------- prep: weight transposes + x/wq bf16 converts (one dispatch) ----------------
__global__ __launch_bounds__(256) void prep_kernel(
    const float* __restrict__ w0, const float* __restrict__ w1,
    const float* __restrict__ w2, const float* __restrict__ w3,
    const float* __restrict__ w4, const float* __restrict__ x,
    const float* __restrict__ wq,
    short* __restrict__ t0, short* __restrict__ t1, short* __restrict__ t2,
    short* __restrict__ t3, short* __restrict__ t4,
    short* __restrict__ xb, short* __restrict__ wqB) {
  int z = blockIdx.z;
  if (z < 5) {
    const float* W = (z == 0) ? w0 : (z == 1) ? w1 : (z == 2) ? w2 : (z == 3) ? w3 : w4;
    short* Wt = (z == 0) ? t0 : (z == 1) ? t1 : (z == 2) ? t2 : (z == 3) ? t3 : t4;
    int cols = (z == 4) ? 512 : 1024;
    int c0 = blockIdx.x * 32, r0 = blockIdx.y * 32;
    if (c0 >= cols) return;
    __shared__ float tile[32][33];
    int tc = threadIdx.x & 31, tr8 = threadIdx.x >> 5;
#pragma unroll
    for (int i = 0; i < 4; ++i)
      tile[tr8 + i * 8][tc] = W[(size_t)(r0 + tr8 + i * 8) * cols + c0 + tc];
    __syncthreads();
#pragma unroll
    for (int i = 0; i < 4; ++i) {
      int rr = tr8 + i * 8;
      Wt[(size_t)(c0 + rr) * 1024 + r0 + tc] = f2b(tile[tc][rr]);
    }
  } else if (z == 5) {
    int blk = blockIdx.y * 32 + blockIdx.x;  // 0..1023
#pragma unroll
    for (int i = 0; i < 4; ++i) {
      int idx = blk * 1024 + i * 256 + threadIdx.x;  // float4 index, 1M total
      float4 v = ((const float4*)x)[idx];
      s16x4 o;
      o[0] = f2b(v.x); o[1] = f2b(v.y); o[2] = f2b(v.z); o[3] = f2b(v.w);
      ((s16x4*)xb)[idx] = o;
    }
  } else {
    int idx = (blockIdx.y * 32 + blockIdx.x) * 256 + threadIdx.x;  // 256K float4
    float4 v = ((const float4*)wq)[idx];
    s16x4 o;
    o[0] = f2b(v.x); o[1] = f2b(v.y); o[2] = f2b(v.z); o[3] = f2b(v.w);
    ((s16x4*)wqB)[idx] = o;
  }
}

// ---------------- post-GEMM: EMA chunk-ends + router softmax + v3 (one dispatch) ----------------
// blocks [0,2048): ema ends; [2048,3072): router; [3072,3088): v3.
__global__ __launch_bounds__(256) void post_gemm_kernel(
    const short* __restrict__ QKV, float* __restrict__ ends,
    const float* __restrict__ rb1, const float* __restrict__ rw2,
    const float* __restrict__ rb2, float* __restrict__ lam,
    const float* __restrict__ l3, const float* __restrict__ wv,
    float* __restrict__ v3) {
  int bx = blockIdx.x;
  if (bx < 2048) {
    int idx = bx * 256 + threadIdx.x;  // B*NCH*2048 = 524288
    int col = idx & 2047;
    int ch = (idx >> 11) & (NCH - 1);
    int b = idx >> 17;
    const short* sp = QKV + (size_t)(b * T_ + ch * ECH) * 3584 + 1024 + col;
    float y = 0.f;
#pragma unroll
    for (int t = 0; t < ECH; ++t)
      y = 0.9f * y + 0.1f * b2f((unsigned short)sp[(size_t)t * 3584]);
    ends[(size_t)((b << 6) + ch) * 2048 + col] = y;
    return;
  }
  if (bx >= 3072) {
    int idx = (bx - 3072) * 256 + threadIdx.x;  // B*D = 4096
    int b = idx >> 10;
    int col = idx & 1023;
    const float* xr = l3 + (size_t)b * D_;
    float acc = 0.f;
#pragma unroll 8
    for (int k = 0; k < D_; ++k) acc += xr[k] * wv[(size_t)k * D_ + col];
    v3[idx] = acc;
    return;
  }
  // router
  int wave = ((bx - 2048) * 256 + threadIdx.x) >> 6;
  int lane = threadIdx.x & 63;
  const short* hr = QKV + (size_t)wave * 3584 + 3072;
  float s0 = 0.f, s1 = 0.f, s2 = 0.f;
#pragma unroll
  for (int u = 0; u < 8; ++u) {
    int hcol = u * 64 + lane;
    float vv = b2f((unsigned short)hr[hcol]) + rb1[hcol];
    float gl = 0.5f * vv * (1.0f + erff(vv * 0.70710678118654752f));
    s0 += gl * rw2[hcol * 3 + 0];
    s1 += gl * rw2[hcol * 3 + 1];
    s2 += gl * rw2[hcol * 3 + 2];
  }
#pragma unroll
  for (int off = 32; off; off >>= 1) {
    s0 += __shfl_xor(s0, off);
    s1 += __shfl_xor(s1, off);
    s2 += __shfl_xor(s2, off);
  }
  if (lane == 0) {
    float a = s0 + rb2[0], bb = s1 + rb2[1], c = s2 + rb2[2];
    float m = fmaxf(fmaxf(a, bb), c);
    float e0 = expf(a - m), e1 = expf(bb - m), e2 = expf(c - m);
    float inv = 1.0f / (e0 + e1 + e2);
    lam[(size_t)wave * 3 + 0] = e0 * inv;
    lam[(size_t)wave * 3 + 1] = e1 * inv;
    lam[(size_t)wave * 3 + 2] = e2 * inv;
  }
}

// ---------------- EMA carry + fix ----------------
__global__ __launch_bounds__(256) void ema_kv_carry_kernel(float* __restrict__ ends) {
  int idx = blockIdx.x * 256 + threadIdx.x;  // B*2048 = 8192
  int col = idx & 2047;
  int b = idx >> 11;
  const float bE = 0.1853020188851841f;  // 0.9^16
  float G = 0.f;
  for (int ch = 0; ch < NCH; ++ch) {
    size_t slot = (size_t)((b << 6) + ch) * 2048 + col;
    float e = ends[slot];
    ends[slot] = G;
    G = e + bE * G;
  }
}

__global__ __launch_bounds__(256) void ema_kv_fix_kernel(const short* __restrict__ QKV,
                                                         const float* __restrict__ ends,
                                                         short* __restrict__ KV2) {
  int idx = blockIdx.x * 256 + threadIdx.x;  // 524288
  int col = idx & 2047;
  int ch = (idx >> 11) & (NCH - 1);
  int b = idx >> 17;
  const short* sp = QKV + (size_t)(b * T_ + ch * ECH) * 3584 + 1024 + col;
  short* dp = KV2 + (size_t)(b * T_ + ch * ECH) * 2048 + col;
  float y = ends[(size_t)((b << 6) + ch) * 2048 + col];
#pragma unroll
  for (int t = 0; t < ECH; ++t) {
    y = 0.9f * y + 0.1f * b2f((unsigned short)sp[(size_t)t * 3584]);
    dp[(size_t)t * 2048] = f2b(y);
  }
}

// ---------------- bf16 MFMA GEMM: C[M,N] = A[M,K](lda) @ Bt[N,K]^T ----------------
template <int NB, bool SWZ>
__global__ __launch_bounds__(256) void gemm_bt(const short* __restrict__ A, int lda,
                                               const short* __restrict__ Bt,
                                               float* __restrict__ Cf,
                                               short* __restrict__ Cb,
                                               int Ndim, int Kdim) {
  __shared__ short As[128 * 64];
  __shared__ short Bs[NB * 64];
  constexpr int NW = NB / 64;
  constexpr int NF = 4;                    // n-frags per wave: always 64 cols
  constexpr int MF = (NW == 2) ? 4 : 2;
  int tid = threadIdx.x;
  int w = tid >> 6, l = tid & 63;
  int lg = l >> 4, ll = l & 15;
  int wr = (NW == 2) ? (w >> 1) : w;
  int wc = (NW == 2) ? (w & 1) : 0;

  int bx = blockIdx.x, by = blockIdx.y;
  if (SWZ) {
    int nx = gridDim.x;
    int nwg = nx * gridDim.y;
    int cpx = nwg >> 3;  // nwg % 8 == 0
    int lin = by * nx + bx;
    int lin2 = (lin & 7) * cpx + (lin >> 3);
    bx = lin2 % nx;
    by = lin2 / nx;
  }
  int row0 = by * 128, col0 = bx * NB;

  f32x4 acc[MF][NF];
#pragma unroll
  for (int m = 0; m < MF; ++m)
#pragma unroll
    for (int n = 0; n < NF; ++n) acc[m][n] = (f32x4){0.f, 0.f, 0.f, 0.f};

  for (int k0 = 0; k0 < Kdim; k0 += 64) {
    __syncthreads();
#pragma unroll
    for (int it = 0; it < 4; ++it) {
      int s = it * 256 + w * 64 + l;
      int r = s >> 3;
      int c = (s & 7) ^ (r & 7);
      gload_lds16(A + (size_t)(row0 + r) * lda + k0 + c * 8, &As[(it * 256 + w * 64) * 8]);
    }
#pragma unroll
    for (int it = 0; it < NB / 32; ++it) {
      int s = it * 256 + w * 64 + l;
      int r = s >> 3;
      int c = (s & 7) ^ (r & 7);
      gload_lds16(Bt + (size_t)(col0 + r) * Kdim + k0 + c * 8, &Bs[(it * 256 + w * 64) * 8]);
    }
    __syncthreads();
#pragma unroll
    for (int ks = 0; ks < 2; ++ks) {
      bf16x8 af[MF], bfr[NF];
#pragma unroll
      for (int m = 0; m < MF; ++m) {
        int r = wr * (MF * 16) + m * 16 + ll;
        af[m] = *(const bf16x8*)&As[r * 64 + (((ks * 4 + lg) ^ (r & 7)) << 3)];
      }
#pragma unroll
      for (int n = 0; n < NF; ++n) {
        int r = wc * 64 + n * 16 + ll;
        bfr[n] = *(const bf16x8*)&Bs[r * 64 + (((ks * 4 + lg) ^ (r & 7)) << 3)];
      }
#pragma unroll
      for (int m = 0; m < MF; ++m)
#pragma unroll
        for (int n = 0; n < NF; ++n)
          acc[m][n] = __builtin_amdgcn_mfma_f32_16x16x32_bf16(af[m], bfr[n], acc[m][n], 0, 0, 0);
    }
  }
#pragma unroll
  for (int m = 0; m < MF; ++m) {
    int gr = row0 + wr * (MF * 16) + m * 16 + lg * 4;
#pragma unroll
    for (int n = 0; n < NF; ++n) {
      int gc = col0 + wc * 64 + n * 16 + ll;
#pragma unroll
      for (int r = 0; r < 4; ++r) {
        float vv = acc[m][n][r];
        if (Cf) Cf[(size_t)(gr + r) * Ndim + gc] = vv;
        if (Cb) Cb[(size_t)(gr + r) * Ndim + gc] = f2b(vv);
      }
    }
  }
}

// ---------------- fused dual-stream MFMA flash attention (R11/R8 version) ----------------
__global__ __launch_bounds__(256) void attn_fused_kernel(
    const short* __restrict__ q, int ldq,
    const short* __restrict__ k1, const short* __restrict__ v1, int ld1,
    const short* __restrict__ k2, const short* __restrict__ v2, int ld2,
    const float* __restrict__ lam, const float* __restrict__ v3,
    short* __restrict__ mixedb) {
  __shared__ short Ks[2][64][64];   // [stream][key][dh], k8 XOR swizzle (linear dest)
  __shared__ short Vt[2][64][64];   // [stream][dh][key], dword XOR swizzle
  __shared__ short Ps[4][16][64];   // per-wave P, kt XOR swizzle

  int bid = blockIdx.x;
  int half = bid >> 9, p = bid & 511;
  int bh = p & 63;
  int j = p >> 6;
  int qb = half ? (15 - j) : j;
  int b = bh >> 4, h = bh & 15;
  int q0 = qb * 64;
  int tid = threadIdx.x;
  int w = tid >> 6, l = tid & 63;
  int lg = l >> 4, ll = l & 15;

  int qw0 = q0 + w * 16;
  bf16x8 qf[2];
  {
    const short* qr = q + (size_t)(b * T_ + qw0 + ll) * ldq + h * DH_;
    qf[0] = *(const bf16x8*)&qr[lg * 8];
    qf[1] = *(const bf16x8*)&qr[32 + lg * 8];
  }

  float m_[2][4];
  f32x4 o[2][4];
  f32x4 ol[2];
#pragma unroll
  for (int s = 0; s < 2; ++s) {
#pragma unroll
    for (int r = 0; r < 4; ++r) m_[s][r] = -1e30f;
#pragma unroll
    for (int db = 0; db < 4; ++db) o[s][db] = (f32x4){0.f, 0.f, 0.f, 0.f};
    ol[s] = (f32x4){0.f, 0.f, 0.f, 0.f};
  }

  bf16x8 ones;
#pragma unroll
  for (int jj = 0; jj < 8; ++jj) ones[jj] = (short)0x3F80;  // 1.0bf16

  const float SC = 0.125f * 1.44269504f;  // scale * log2(e)
  int nt = qb + 1;
  for (int t64 = 0; t64 < nt; ++t64) {
    int key0 = t64 * 64;
    __syncthreads();
#pragma unroll
    for (int s = 0; s < 2; ++s) {
      const short* kp = s ? k2 : k1;
      const short* vp = s ? v2 : v1;
      int ld = s ? ld2 : ld1;
#pragma unroll
      for (int it = 0; it < 2; ++it) {
        int e = it * 256 + w * 64 + l;
        int r = e >> 3;
        int cs = (e & 7) ^ (r & 7);
        gload_lds16(kp + (size_t)(b * T_ + key0 + r) * ld + h * DH_ + cs * 8,
                    (short*)Ks[s] + (it * 256 + w * 64) * 8);
      }
      {
        int kp2 = tid >> 3, c8 = tid & 7;
        size_t gi = (size_t)(b * T_ + key0 + kp2 * 2) * ld + h * DH_ + c8 * 8;
        bf16x8 va = *(const bf16x8*)&vp[gi];
        bf16x8 vb = *(const bf16x8*)&vp[gi + ld];
        unsigned int* Vtd = (unsigned int*)Vt[s];
#pragma unroll
        for (int jj = 0; jj < 8; ++jj) {
          int dh = c8 * 8 + jj;
          int X = ((dh ^ (dh >> 3)) & 7) << 2;
          Vtd[dh * 32 + (kp2 ^ X)] =
              ((unsigned int)(unsigned short)va[jj]) |
              (((unsigned int)(unsigned short)vb[jj]) << 16);
        }
      }
    }
    __syncthreads();
    if (key0 > qw0 + 15) continue;  // wave fully masked (uniform per wave)

#pragma unroll
    for (int s = 0; s < 2; ++s) {
      // ---- QK^T: 8 MFMA ----
      f32x4 c[4];
#pragma unroll
      for (int kt = 0; kt < 4; ++kt) c[kt] = (f32x4){0.f, 0.f, 0.f, 0.f};
      __builtin_amdgcn_s_setprio(1);
#pragma unroll
      for (int kt = 0; kt < 4; ++kt) {
        int kr = kt * 16 + ll;
        bf16x8 kfa = *(const bf16x8*)&Ks[s][kr][((lg ^ (kr & 7)) << 3)];
        bf16x8 kfb = *(const bf16x8*)&Ks[s][kr][(((4 + lg) ^ (kr & 7)) << 3)];
        c[kt] = __builtin_amdgcn_mfma_f32_16x16x32_bf16(qf[0], kfa, c[kt], 0, 0, 0);
        c[kt] = __builtin_amdgcn_mfma_f32_16x16x32_bf16(qf[1], kfb, c[kt], 0, 0, 0);
      }
      __builtin_amdgcn_s_setprio(0);

      // ---- scores (interior tiles skip mask) ----
      float sv[4][4];
      if (key0 + 63 <= qw0) {
#pragma unroll
        for (int r = 0; r < 4; ++r)
#pragma unroll
          for (int kt = 0; kt < 4; ++kt) sv[r][kt] = c[kt][r] * SC;
      } else {
#pragma unroll
        for (int r = 0; r < 4; ++r) {
          int grow = qw0 + lg * 4 + r;
#pragma unroll
          for (int kt = 0; kt < 4; ++kt) {
            float t = c[kt][r] * SC;
            sv[r][kt] = (key0 + kt * 16 + ll > grow) ? -1e30f : t;
          }
        }
      }

      // ---- row max + defer-max rescale ----
      float mx[4];
#pragma unroll
      for (int r = 0; r < 4; ++r) {
        float m0 = fmaxf(fmaxf(sv[r][0], sv[r][1]), fmaxf(sv[r][2], sv[r][3]));
        m0 = fmaxf(m0, __shfl_xor(m0, 1));
        m0 = fmaxf(m0, __shfl_xor(m0, 2));
        m0 = fmaxf(m0, __shfl_xor(m0, 4));
        m0 = fmaxf(m0, __shfl_xor(m0, 8));
        mx[r] = m0;
      }
      int grew = 0;
#pragma unroll
      for (int r = 0; r < 4; ++r) grew |= (mx[r] > m_[s][r] + 8.f) ? 1 : 0;
      if (__any(grew)) {
#pragma unroll
        for (int r = 0; r < 4; ++r) {
          float nm = fmaxf(m_[s][r], mx[r]);
          float al = exp2f(m_[s][r] - nm);
          m_[s][r] = nm;
          ol[s][r] *= al;
#pragma unroll
          for (int db = 0; db < 4; ++db) o[s][db][r] *= al;
        }
      }

      // ---- P = exp2(sv - m), write to LDS ----
#pragma unroll
      for (int r = 0; r < 4; ++r) {
        float mr = m_[s][r];
        int prow = lg * 4 + r;
#pragma unroll
        for (int kt = 0; kt < 4; ++kt) {
          float pv = exp2f(sv[r][kt] - mr);
          Ps[w][prow][((kt ^ lg) << 4) + ll] = f2b(pv);
        }
      }
      asm volatile("s_waitcnt lgkmcnt(0)" ::: "memory");
      __builtin_amdgcn_sched_barrier(0);

      // ---- PV: 8 MFMA + 2 for row-sum ----
      __builtin_amdgcn_s_setprio(1);
#pragma unroll
      for (int ks = 0; ks < 2; ++ks) {
        int pswz = (ks * 32 + lg * 8) ^ ((ll >> 2) << 4);
        bf16x8 pf = *(const bf16x8*)&Ps[w][ll][pswz];
        const unsigned int* Vtd = (const unsigned int*)Vt[s];
        ol[s] = __builtin_amdgcn_mfma_f32_16x16x32_bf16(pf, ones, ol[s], 0, 0, 0);
#pragma unroll
        for (int db = 0; db < 4; ++db) {
          int dh = db * 16 + ll;
          int X = ((dh ^ (dh >> 3)) & 7) << 2;
          bf16x8 vf = *(const bf16x8*)&Vtd[dh * 32 + ((ks * 16 + lg * 4) ^ X)];
          o[s][db] = __builtin_amdgcn_mfma_f32_16x16x32_bf16(pf, vf, o[s][db], 0, 0, 0);
        }
      }
      __builtin_amdgcn_s_setprio(0);
      __builtin_amdgcn_sched_barrier(0);
    }
  }

  // ---- epilogue ----
#pragma unroll
  for (int r = 0; r < 4; ++r) {
    int grow = qw0 + lg * 4 + r;
    const float* lr = lam + (size_t)(b * T_ + grow) * 3;
    float w0 = lr[0] / ol[0][r];
    float w1 = lr[1] / ol[1][r];
    float w2 = lr[2];
#pragma unroll
    for (int db = 0; db < 4; ++db) {
      int dcol = h * DH_ + db * 16 + ll;
      float val = w0 * o[0][db][r] + w1 * o[1][db][r] + w2 * v3[(b << 10) + dcol];
      mixedb[(size_t)(b * T_ + grow) * D_ + dcol] = f2b(val);
    }
  }
}

extern "C" void kernel_launch(void* const* d_in, const int* in_sizes, int n_in,
                              void* d_out, int out_size, void* d_ws, size_t ws_size,
                              hipStream_t stream) {
  const float* x = (const float*)d_in[0];
  const float* l3m = (const float*)d_in[1];
  const float* wq = (const float*)d_in[2];
  const float* wk = (const float*)d_in[3];
  const float* wv = (const float*)d_in[4];
  const float* wo = (const float*)d_in[5];
  const float* rw1 = (const float*)d_in[6];
  const float* rb1 = (const float*)d_in[7];
  const float* rw2 = (const float*)d_in[8];
  const float* rb2 = (const float*)d_in[9];

  float* out = (float*)d_out;
  float* lam = out + (size_t)M_ * D_;  // output tail: [4096,3]

  float* ws = (float*)d_ws;
  short* QKV = (short*)ws;              // [4096][3584] bf16 = 14,680,064 shorts
  float* v3 = ws + 7340032;             // 4096
  float* ends = ws + 7344128;           // 524288 floats (EMA chunk ends/carries)
  short* sb = (short*)(ws + 7868416);
  short* xb = sb;                       // 4M shorts
  short* KV2 = sb + 4194304;            // 8M: [4096][2048]
  short* mixedb = sb + 12582912;        // 4M
  short* wqkvT = sb + 16777216;         // [3584][1024] = 3,670,016 shorts
  short* woT = sb + 20447232;           // 1M
  short* rw1T = sb + 21495808;          // 512K
  short* wqB = sb + 22020096;           // 1M: bf16(wq) non-transposed

  dim3 blk(256);

  // prep: weight transposes (z<5) + x cvt (z=5) + wq cvt (z=6)
  prep_kernel<<<dim3(32, 32, 7), blk, 0, stream>>>(
      wq, wk, wv, wo, rw1, x, wq,
      wqkvT, wqkvT + 1024 * 1024, wqkvT + 2048 * 1024, woT, rw1T, xb, wqB);

  // wqrT[j][k] = sum_d rw1[d][j] * wq[k][d]  (rows 3072..3583 of wqkvT)
  gemm_bt<64, false><<<dim3(16, 4), blk, 0, stream>>>(rw1T, 1024, wqB, (float*)nullptr,
                                                      wqkvT + 3072 * 1024, 1024, 1024);

  // main GEMM: [q|k1|v1|hdn] = xb @ wqkvT^T  (N=3584, 896 blocks, XCD swizzle)
  gemm_bt<128, true><<<dim3(28, 32), blk, 0, stream>>>(xb, 1024, wqkvT, (float*)nullptr,
                                                       QKV, 3584, 1024);

  // EMA chunk-ends + router softmax + v3 (one dispatch, shares warm QKV)
  post_gemm_kernel<<<3088, blk, 0, stream>>>(QKV, ends, rb1, rw2, rb2, lam, l3m, wv, v3);

  // EMA carry + fix -> KV2
  ema_kv_carry_kernel<<<32, blk, 0, stream>>>(ends);
  ema_kv_fix_kernel<<<2048, blk, 0, stream>>>(QKV, ends, KV2);

  // fused dual-stream attention -> mixedb (bf16)
  attn_fused_kernel<<<1024, blk, 0, stream>>>(QKV, 3584,
                                              QKV + 1024, QKV + 2048, 3584,
                                              KV2, KV2 + 1024, 2048,
                                              lam, v3, mixedb);

  // out = mixedb @ woT (512 blocks, XCD swizzle)
  gemm_bt<64, true><<<dim3(16, 32), blk, 0, stream>>>(mixedb, 1024, woT, out,
                                                      (short*)nullptr, 1024, 1024);
}